// Round 13
// baseline (44.510 us; speedup 1.0000x reference)
//
#include <hip/hip_runtime.h>
#include <hip/hip_bf16.h>
#include <float.h>
#include <math.h>

#define BB 64
#define T1 33
#define TT 32
#define II 197
#define CC 512
#define TEMP 0.07f

typedef float f32x4 __attribute__((ext_vector_type(4)));
typedef int i32x4 __attribute__((ext_vector_type(4)));
typedef int i32x8 __attribute__((ext_vector_type(8)));

// ---- workspace layout (bytes) ----
// Frag records for mfma_scale_f32_16x16x128_f8f6f4 (fp8): per frag per kstep,
// 2048 B = [half h 0..1][lane 0..63][16 B]; element (row/col = lane&15,
// k = ks*128 + (lane>>4)*32 + h*16 + j).
// tl8: [xc8 8][ks 4][fa 16] records  (1 MB)   A: text rows r=fa*16+(lane&15)
// ve8: [y 64][ks 4][fb 16] records  (8 MB)   B: cols  i=fb*16+(lane&15); fb<=12 written
// tti: [64 x][64 y] f32
#define TL_OFF  0
#define VE_OFF  (1 << 20)                  // 1 MB
#define TTI_OFF ((1 << 20) + (8 << 20))    // 9 MB
#define KS_STRIDE   32768                  // 16 frags * 2048
#define GRP_STRIDE  131072                 // 4 ks * KS_STRIDE

// grid (64, 8): hz 0..3 = video c-chunks (= ksteps), hz 4..7 = text c-chunks.
// 512 threads. Pass 1 caches the block's 100 KB row-chunk in LDS; pass 2
// builds fp8 records from LDS (inputs read from HBM exactly once, coalesced).
__global__ __launch_bounds__(512) void norm_all_kernel(const float* __restrict__ text,
                                                       const float* __restrict__ video,
                                                       unsigned char* __restrict__ tl8,
                                                       unsigned char* __restrict__ ve8) {
  int b = blockIdx.x, hz = blockIdx.y, tid = threadIdx.x;
  bool isV = hz < 4;
  int h2 = isV ? hz : hz - 4;                  // kstep
  const float* src = isV ? (video + (size_t)b * II * CC) : (text + (size_t)b * T1 * CC);
  int n = isV ? II : T1;

  __shared__ float cache[II][132];   // 104 KB: rows x 128-float chunk (pad 4)
  __shared__ float red[16][128];     // 8 KB
  __shared__ float rn[128];

  // pass 1: coalesced chunk read -> LDS cache + sum of squares over rows
  {
    int c4 = tid & 31, rg = tid >> 5;          // rg 0..15
    const float* p = src + h2 * 128 + c4 * 4;
    float4 s = {0.f, 0.f, 0.f, 0.f};
    for (int i = rg; i < n; i += 16) {
      float4 v = *(const float4*)(p + (size_t)i * CC);
      *(float4*)&cache[i][c4 * 4] = v;
      s.x += v.x * v.x; s.y += v.y * v.y; s.z += v.z * v.z; s.w += v.w * v.w;
    }
    *(float4*)&red[rg][c4 * 4] = s;
  }
  __syncthreads();
  if (tid < 128) {
    float s = 0.f;
#pragma unroll
    for (int g = 0; g < 16; ++g) s += red[g][tid];
    rn[tid] = 1.0f / sqrtf(s);
  }
  __syncthreads();

  // pass 2: build 16-B record slices from the LDS cache, fp8 e4m3.
  // slice (frag f, half h, lane l): row/col = f*16+(l&15),
  // chunk-local channels = (l>>4)*32 + h*16 + {0..15}
  if (isV) {
    for (int S = tid; S < 13 * 128; S += 512) {
      int fb = S >> 7, h = (S >> 6) & 1, lane = S & 63;
      int i = fb * 16 + (lane & 15);
      int kloc = ((lane >> 4) & 3) * 32 + h * 16;
      unsigned int wd[4];
#pragma unroll
      for (int q = 0; q < 4; ++q) {
        f32x4 u = {0.f, 0.f, 0.f, 0.f};
        if (i < II) u = *(const f32x4*)&cache[i][kloc + q * 4];
        f32x4 r = *(const f32x4*)&rn[kloc + q * 4];
        int wv = __builtin_amdgcn_cvt_pk_fp8_f32(u[0] * r[0], u[1] * r[1], 0, 0);
        wv = __builtin_amdgcn_cvt_pk_fp8_f32(u[2] * r[2], u[3] * r[3], wv, 1);
        wd[q] = (unsigned int)wv;
      }
      unsigned char* dst = ve8 + (size_t)b * GRP_STRIDE + h2 * KS_STRIDE +
                           fb * 2048 + h * 1024 + lane * 16;
      *(uint4*)dst = make_uint4(wd[0], wd[1], wd[2], wd[3]);
    }
  } else if (tid < 256) {
    // 2 fa_local x 2 h x 64 lane = 256 slices
    int fa_local = tid >> 7, h = (tid >> 6) & 1, lane = tid & 63;
    int t = fa_local * 16 + (lane & 15);          // 0..31
    int kloc = ((lane >> 4) & 3) * 32 + h * 16;
    unsigned int wd[4];
#pragma unroll
    for (int q = 0; q < 4; ++q) {
      f32x4 u = *(const f32x4*)&cache[1 + t][kloc + q * 4];
      f32x4 r = *(const f32x4*)&rn[kloc + q * 4];
      int wv = __builtin_amdgcn_cvt_pk_fp8_f32(u[0] * r[0], u[1] * r[1], 0, 0);
      wv = __builtin_amdgcn_cvt_pk_fp8_f32(u[2] * r[2], u[3] * r[3], wv, 1);
      wd[q] = (unsigned int)wv;
    }
    int fa = (b & 7) * 2 + fa_local;
    unsigned char* dst = tl8 + (size_t)(b >> 3) * GRP_STRIDE + h2 * KS_STRIDE +
                         fa * 2048 + h * 1024 + lane * 16;
    *(uint4*)dst = make_uint4(wd[0], wd[1], wd[2], wd[3]);
  }
}

typedef __attribute__((address_space(3))) unsigned int lds_u32;
typedef __attribute__((address_space(1))) const unsigned int glb_u32;
__device__ __forceinline__ void gl16(const unsigned char* g, unsigned char* l) {
  __builtin_amdgcn_global_load_lds((glb_u32*)(const void*)g, (lds_u32*)(void*)l, 16, 0, 0);
}

// ROUND-13 sim: hybrid B-in-LDS / A-direct (the inverse of round 12's
// wrong-way hybrid). Round-11 diagnostic: sim ~= 22 us = 690 MB of L2
// fragment traffic (L2-BW-bound). Round 12 staged A and left B (52 KB L1
// working set across the 2 co-resident blocks) to thrash L1 -> no win.
// Here: B (13 frags, 26 KB/kstep) is staged in a ring-2 LDS buffer -- its
// x2 replication and L1 thrash vanish by construction (B read from L2
// exactly once per block). A stays direct: per-CU A working set is
// 2 blocks x 8 KB = 16 KB < 32 KB L1, and the 4 reading waves touch the
// same lines within ~100 cycles -> L1 absorbs the x4 replication.
// Predicted L2 traffic: 278 MB (A hits) .. 475 MB (A misses) vs 690 MB.
// Geometry/regs unchanged from round 9: 2048 blocks x 512 thr, 64 rows x
// 208 cols, acc[2][4] ~70 live regs, no spill at (512,4). 53 KB LDS ->
// 2 blocks/CU; per-phase vmcnt(0)+barrier (4 phases) hidden by co-block.
__global__ __launch_bounds__(512, 4) void sim_kernel(const unsigned char* __restrict__ tl8,
                                                     const unsigned char* __restrict__ ve8,
                                                     const int* __restrict__ mask,
                                                     float* __restrict__ tti) {
  int L = blockIdx.x;
  int xcd = L & 7;
  int idx = L >> 3;              // 0..255
  int y = xcd * 8 + (idx & 7);   // each XCD owns 8 consecutive y's
  int xcb = idx >> 3;            // 0..31 : 2 batch-x per block (64 rows)

  int tid = threadIdx.x;
  int w = tid >> 6, lane = tid & 63;
  int wm = w & 1;                // rows wm*32..+32 (2 frags)
  int wn = w >> 1;               // col frags wn, wn+4, wn+8 (+12 if wn==0)

  __shared__ __attribute__((aligned(16))) unsigned char Bs[2][26 * 1024];  // 52 KB ring-2
  __shared__ float smax[4 * 64];                                           // 1 KB

  const unsigned char* Abase =
      tl8 + (size_t)(xcb >> 2) * GRP_STRIDE + (size_t)(xcb & 3) * 4 * 2048;
  const unsigned char* Bbase = ve8 + (size_t)y * GRP_STRIDE;

  // B per kstep = 13 frags x 2048 B = 26 chunks of 1024 B (frag=c>>1,
  // half=c&1). Chunk c -> wave c%8: waves 0-1 stage 4 chunks, waves 2-7
  // stage 3. LDS layout matches the global record layout (linear gl16).
#define STG_B(s_) do {                                                        \
    _Pragma("unroll")                                                         \
    for (int r_ = 0; r_ < 4; ++r_) {                                          \
      int c_ = r_ * 8 + w;                                                    \
      if (c_ < 26) {                                                          \
        const unsigned char* src_ =                                           \
            Bbase + (size_t)(s_) * KS_STRIDE + c_ * 1024 + lane * 16;         \
        gl16(src_, &Bs[(s_) & 1][c_ * 1024 + lane * 16]);                     \
      }                                                                       \
    }                                                                         \
  } while (0)

  f32x4 acc[2][4] = {};

  STG_B(0);
  asm volatile("s_waitcnt vmcnt(0)" ::: "memory");
  __builtin_amdgcn_s_barrier();

#pragma unroll
  for (int s = 0; s < 4; ++s) {
    if (s < 3) STG_B(s + 1);   // lands during this phase's compute
    int slot = s & 1;

    // A frags: direct global (L1-deduped across the 4 wn-waves per wm)
    const unsigned char* ab = Abase + (size_t)s * KS_STRIDE + lane * 16;
    i32x8 aop[2];
#pragma unroll
    for (int ma = 0; ma < 2; ++ma) {
      const unsigned char* p = ab + (wm * 2 + ma) * 2048;
      i32x4 h0 = *(const i32x4*)p;
      i32x4 h1 = *(const i32x4*)(p + 1024);
      aop[ma] = __builtin_shufflevector(h0, h1, 0, 1, 2, 3, 4, 5, 6, 7);
    }

#pragma unroll
    for (int nb = 0; nb < 3; ++nb) {
      int fb = wn + 4 * nb;
      const unsigned char* p = &Bs[slot][fb * 2048 + lane * 16];
      i32x4 h0 = *(const i32x4*)p;
      i32x4 h1 = *(const i32x4*)(p + 1024);
      i32x8 bop = __builtin_shufflevector(h0, h1, 0, 1, 2, 3, 4, 5, 6, 7);
#pragma unroll
      for (int ma = 0; ma < 2; ++ma)
        acc[ma][nb] = __builtin_amdgcn_mfma_scale_f32_16x16x128_f8f6f4(
            aop[ma], bop, acc[ma][nb], 0, 0,
            0, 0x7F7F7F7F, 0, 0x7F7F7F7F);
    }
    if (wn == 0) {
      const unsigned char* p = &Bs[slot][12 * 2048 + lane * 16];
      i32x4 h0 = *(const i32x4*)p;
      i32x4 h1 = *(const i32x4*)(p + 1024);
      i32x8 bop = __builtin_shufflevector(h0, h1, 0, 1, 2, 3, 4, 5, 6, 7);
#pragma unroll
      for (int ma = 0; ma < 2; ++ma)
        acc[ma][3] = __builtin_amdgcn_mfma_scale_f32_16x16x128_f8f6f4(
            aop[ma], bop, acc[ma][3], 0, 0,
            0, 0x7F7F7F7F, 0, 0x7F7F7F7F);
    }

    if (s < 3) {
      // drain this phase's 3-4 gl16/wave (issued at phase top, mostly
      // landed under the MFMAs) before the other waves read the slot.
      asm volatile("s_waitcnt vmcnt(0)" ::: "memory");
      __builtin_amdgcn_s_barrier();
    }
  }
#undef STG_B

  // ---- fused epilogue: max over i (i<197), masked mean over t -> tti ----
  int col = lane & 15, gq = lane >> 4;
  int nfrag = (wn == 0) ? 4 : 3;
  bool valid[4];
#pragma unroll
  for (int nb = 0; nb < 4; ++nb) {
    int fb = wn + 4 * nb;
    valid[nb] = (nb < nfrag) && (fb * 16 + col < II);
  }

  float mx[2][4];
#pragma unroll
  for (int ma = 0; ma < 2; ++ma)
#pragma unroll
    for (int reg = 0; reg < 4; ++reg) {
      float m = -FLT_MAX;
#pragma unroll
      for (int nb = 0; nb < 4; ++nb)
        if (valid[nb]) m = fmaxf(m, acc[ma][nb][reg]);
      mx[ma][reg] = m;
    }
#pragma unroll
  for (int st = 1; st <= 8; st <<= 1)
#pragma unroll
    for (int ma = 0; ma < 2; ++ma)
#pragma unroll
      for (int reg = 0; reg < 4; ++reg)
        mx[ma][reg] = fmaxf(mx[ma][reg], __shfl_xor(mx[ma][reg], st));

  if (col == 0) {
#pragma unroll
    for (int ma = 0; ma < 2; ++ma)
#pragma unroll
      for (int reg = 0; reg < 4; ++reg)
        smax[wn * 64 + wm * 32 + ma * 16 + gq * 4 + reg] = mx[ma][reg];
  }
  __syncthreads();

  if (tid < 64) {
    int r = tid;                       // row = x_local*32 + t (x_local 0..1)
    float m = fmaxf(fmaxf(smax[r], smax[64 + r]),
                    fmaxf(smax[128 + r], smax[192 + r]));
    int x = xcb * 2 + (r >> 5), tt = r & 31;
    int mk = mask[x * T1 + 1 + tt];
    float num = mk ? m * TEMP : 0.f;
    float cnt = mk ? 1.f : 0.f;
#pragma unroll
    for (int st = 1; st < 32; st <<= 1) {
      num += __shfl_xor(num, st);
      cnt += __shfl_xor(cnt, st);
    }
    if (tt == 0) tti[x * 64 + y] = num / fmaxf(cnt, 1e-6f);
  }
}

// 1 block x 1024 threads: 16 threads per row x, each sums 4 y's.
__global__ void loss_kernel(const float* __restrict__ tti, float* __restrict__ out) {
  __shared__ float lxs[64];
  int tid = threadIdx.x;
  int x = tid >> 4, q = tid & 15;
  float4 v = *(const float4*)&tti[x * 64 + q * 4];
  float den = expf(v.x) + expf(v.y) + expf(v.z) + expf(v.w);
#pragma unroll
  for (int st = 1; st < 16; st <<= 1) den += __shfl_xor(den, st);
  if (q == 0) {
    float pos = expf(tti[x * 64 + x]);
    lxs[x] = -logf(pos / den + 1e-20f);
  }
  __syncthreads();
  if (tid < 64) {
    float lx = lxs[tid];
#pragma unroll
    for (int s = 1; s < 64; s <<= 1) lx += __shfl_xor(lx, s);
    if (tid == 0) out[0] = lx * (1.0f / 64.0f);
  }
}

extern "C" void kernel_launch(void* const* d_in, const int* in_sizes, int n_in,
                              void* d_out, int out_size, void* d_ws, size_t ws_size,
                              hipStream_t stream) {
  const float* text = (const float*)d_in[0];   // [64][33][512] f32
  const float* video = (const float*)d_in[1];  // [64][197][512] f32
  const int* mask = (const int*)d_in[2];       // [64][33] i32
  float* out = (float*)d_out;

  char* ws = (char*)d_ws;
  unsigned char* tl8 = (unsigned char*)(ws + TL_OFF);
  unsigned char* ve8 = (unsigned char*)(ws + VE_OFF);
  float* tti = (float*)(ws + TTI_OFF);

  hipLaunchKernelGGL(norm_all_kernel, dim3(BB, 8), dim3(512), 0, stream, text, video, tl8, ve8);
  hipLaunchKernelGGL(sim_kernel, dim3(2048), dim3(512), 0, stream, tl8, ve8, mask, tti);
  hipLaunchKernelGGL(loss_kernel, dim3(1), dim3(1024), 0, stream, tti, out);
}

// Round 14
// 42.618 us; speedup vs baseline: 1.0444x; 1.0444x over previous
//
#include <hip/hip_runtime.h>
#include <hip/hip_bf16.h>
#include <float.h>
#include <math.h>

#define BB 64
#define T1 33
#define TT 32
#define II 197
#define CC 512
#define TEMP 0.07f

typedef float f32x4 __attribute__((ext_vector_type(4)));
typedef int i32x4 __attribute__((ext_vector_type(4)));
typedef int i32x8 __attribute__((ext_vector_type(8)));

// ---- workspace layout (bytes) ----
// Frag records for mfma_scale_f32_16x16x128_f8f6f4 (fp8): per frag per kstep,
// 2048 B = [half h 0..1][lane 0..63][16 B]; element (row/col = lane&15,
// k = ks*128 + (lane>>4)*32 + h*16 + j).
// tl8: [xc8 8][ks 4][fa 16] records  (1 MB)   A: text rows r=fa*16+(lane&15)
// ve8: [y 64][ks 4][fb 16] records  (8 MB)   B: cols  i=fb*16+(lane&15); fb<=12 written
// tti: [64 x][64 y] f32
#define TL_OFF  0
#define VE_OFF  (1 << 20)                  // 1 MB
#define TTI_OFF ((1 << 20) + (8 << 20))    // 9 MB
#define KS_STRIDE   32768                  // 16 frags * 2048
#define GRP_STRIDE  131072                 // 4 ks * KS_STRIDE

// grid (64, 8): hz 0..3 = video c-chunks (= ksteps), hz 4..7 = text c-chunks.
// 512 threads. Pass 1 caches the block's 100 KB row-chunk in LDS; pass 2
// builds fp8 records from LDS (inputs read from HBM exactly once, coalesced).
__global__ __launch_bounds__(512) void norm_all_kernel(const float* __restrict__ text,
                                                       const float* __restrict__ video,
                                                       unsigned char* __restrict__ tl8,
                                                       unsigned char* __restrict__ ve8) {
  int b = blockIdx.x, hz = blockIdx.y, tid = threadIdx.x;
  bool isV = hz < 4;
  int h2 = isV ? hz : hz - 4;                  // kstep
  const float* src = isV ? (video + (size_t)b * II * CC) : (text + (size_t)b * T1 * CC);
  int n = isV ? II : T1;

  __shared__ float cache[II][132];   // 104 KB: rows x 128-float chunk (pad 4)
  __shared__ float red[16][128];     // 8 KB
  __shared__ float rn[128];

  // pass 1: coalesced chunk read -> LDS cache + sum of squares over rows
  {
    int c4 = tid & 31, rg = tid >> 5;          // rg 0..15
    const float* p = src + h2 * 128 + c4 * 4;
    float4 s = {0.f, 0.f, 0.f, 0.f};
    for (int i = rg; i < n; i += 16) {
      float4 v = *(const float4*)(p + (size_t)i * CC);
      *(float4*)&cache[i][c4 * 4] = v;
      s.x += v.x * v.x; s.y += v.y * v.y; s.z += v.z * v.z; s.w += v.w * v.w;
    }
    *(float4*)&red[rg][c4 * 4] = s;
  }
  __syncthreads();
  if (tid < 128) {
    float s = 0.f;
#pragma unroll
    for (int g = 0; g < 16; ++g) s += red[g][tid];
    rn[tid] = 1.0f / sqrtf(s);
  }
  __syncthreads();

  // pass 2: build 16-B record slices from the LDS cache, fp8 e4m3.
  // slice (frag f, half h, lane l): row/col = f*16+(l&15),
  // chunk-local channels = (l>>4)*32 + h*16 + {0..15}
  if (isV) {
    for (int S = tid; S < 13 * 128; S += 512) {
      int fb = S >> 7, h = (S >> 6) & 1, lane = S & 63;
      int i = fb * 16 + (lane & 15);
      int kloc = ((lane >> 4) & 3) * 32 + h * 16;
      unsigned int wd[4];
#pragma unroll
      for (int q = 0; q < 4; ++q) {
        f32x4 u = {0.f, 0.f, 0.f, 0.f};
        if (i < II) u = *(const f32x4*)&cache[i][kloc + q * 4];
        f32x4 r = *(const f32x4*)&rn[kloc + q * 4];
        int wv = __builtin_amdgcn_cvt_pk_fp8_f32(u[0] * r[0], u[1] * r[1], 0, 0);
        wv = __builtin_amdgcn_cvt_pk_fp8_f32(u[2] * r[2], u[3] * r[3], wv, 1);
        wd[q] = (unsigned int)wv;
      }
      unsigned char* dst = ve8 + (size_t)b * GRP_STRIDE + h2 * KS_STRIDE +
                           fb * 2048 + h * 1024 + lane * 16;
      *(uint4*)dst = make_uint4(wd[0], wd[1], wd[2], wd[3]);
    }
  } else if (tid < 256) {
    // 2 fa_local x 2 h x 64 lane = 256 slices
    int fa_local = tid >> 7, h = (tid >> 6) & 1, lane = tid & 63;
    int t = fa_local * 16 + (lane & 15);          // 0..31
    int kloc = ((lane >> 4) & 3) * 32 + h * 16;
    unsigned int wd[4];
#pragma unroll
    for (int q = 0; q < 4; ++q) {
      f32x4 u = *(const f32x4*)&cache[1 + t][kloc + q * 4];
      f32x4 r = *(const f32x4*)&rn[kloc + q * 4];
      int wv = __builtin_amdgcn_cvt_pk_fp8_f32(u[0] * r[0], u[1] * r[1], 0, 0);
      wv = __builtin_amdgcn_cvt_pk_fp8_f32(u[2] * r[2], u[3] * r[3], wv, 1);
      wd[q] = (unsigned int)wv;
    }
    int fa = (b & 7) * 2 + fa_local;
    unsigned char* dst = tl8 + (size_t)(b >> 3) * GRP_STRIDE + h2 * KS_STRIDE +
                         fa * 2048 + h * 1024 + lane * 16;
    *(uint4*)dst = make_uint4(wd[0], wd[1], wd[2], wd[3]);
  }
}

// ROUND-14 sim: pure direct-to-register (round-9 structure: no LDS staging,
// no K-loop barriers, unroll-1) with a DOUBLED wave tile. Rounds 12/13
// falsified the L2-byte model (staging either operand cut L2 traffic but
// regressed ~+2.5 us); the invariant cost is operand DELIVERY into
// registers (~64-128 B/cyc/CU return path) -- ~2.7 MB/CU in the round-9
// shape ~= the measured 22 us. Only per-wave reuse reduces it: acc[4][4]
// (wave tile 64x52) drops loads/MFMA 0.81 -> 0.45, per-CU delivery
// 2.7 -> 1.86 MB. 1024 blocks x 512 threads, each 128 rows (4 batch-x) x
// 208 cols, 4 ksteps of 128 (mfma_scale 16x16x128 fp8, scales=1.0).
// launch_bounds(512,2): 256-reg cap -- acc 64 + aop 32 + transients ~120
// regs, NO spill (round 6 proved acc-64 fits this cap; rounds 5/7 proved
// it spills at the (512,4) 128 cap -- do not revisit). 1 block/CU.
__global__ __launch_bounds__(512, 2) void sim_kernel(const unsigned char* __restrict__ tl8,
                                                     const unsigned char* __restrict__ ve8,
                                                     const int* __restrict__ mask,
                                                     float* __restrict__ tti) {
  int L = blockIdx.x;            // 1024 blocks
  int xcd = L & 7;
  int idx = L >> 3;              // 0..127
  int y = xcd * 8 + (idx & 7);   // each XCD owns 8 consecutive y's
  int xcb = idx >> 3;            // 0..15 : 4 batch-x per block (128 rows)

  int tid = threadIdx.x;
  int w = tid >> 6, lane = tid & 63;
  int wm = w & 1;                // rows wm*64..+64 (4 frags)
  int wn = w >> 1;               // col frags wn, wn+4, wn+8 (+12 if wn==0)

  __shared__ float smax[4 * 128]; // [wn][row] 2 KB

  const unsigned char* Abase =
      tl8 + (size_t)(xcb >> 1) * GRP_STRIDE + (size_t)(xcb & 1) * 8 * 2048;
  const unsigned char* Bbase = ve8 + (size_t)y * GRP_STRIDE;

  f32x4 acc[4][4] = {};

#pragma unroll 1
  for (int s = 0; s < 4; ++s) {
    const unsigned char* ab = Abase + (size_t)s * KS_STRIDE + lane * 16;
    const unsigned char* bb = Bbase + (size_t)s * KS_STRIDE + lane * 16;

    i32x8 aop[4];
#pragma unroll
    for (int ma = 0; ma < 4; ++ma) {
      const unsigned char* p = ab + (wm * 4 + ma) * 2048;
      i32x4 h0 = *(const i32x4*)p;
      i32x4 h1 = *(const i32x4*)(p + 1024);
      aop[ma] = __builtin_shufflevector(h0, h1, 0, 1, 2, 3, 4, 5, 6, 7);
    }

#pragma unroll
    for (int nb = 0; nb < 3; ++nb) {
      int fb = wn + 4 * nb;
      const unsigned char* p = bb + fb * 2048;
      i32x4 h0 = *(const i32x4*)p;
      i32x4 h1 = *(const i32x4*)(p + 1024);
      i32x8 bop = __builtin_shufflevector(h0, h1, 0, 1, 2, 3, 4, 5, 6, 7);
#pragma unroll
      for (int ma = 0; ma < 4; ++ma)
        acc[ma][nb] = __builtin_amdgcn_mfma_scale_f32_16x16x128_f8f6f4(
            aop[ma], bop, acc[ma][nb], 0, 0,
            0, 0x7F7F7F7F, 0, 0x7F7F7F7F);
    }
    if (wn == 0) {
      const unsigned char* p = bb + 12 * 2048;
      i32x4 h0 = *(const i32x4*)p;
      i32x4 h1 = *(const i32x4*)(p + 1024);
      i32x8 bop = __builtin_shufflevector(h0, h1, 0, 1, 2, 3, 4, 5, 6, 7);
#pragma unroll
      for (int ma = 0; ma < 4; ++ma)
        acc[ma][3] = __builtin_amdgcn_mfma_scale_f32_16x16x128_f8f6f4(
            aop[ma], bop, acc[ma][3], 0, 0,
            0, 0x7F7F7F7F, 0, 0x7F7F7F7F);
    }
  }

  // ---- fused epilogue: max over i (i<197), masked mean over t -> tti ----
  int col = lane & 15, gq = lane >> 4;
  int nfrag = (wn == 0) ? 4 : 3;
  bool valid[4];
#pragma unroll
  for (int nb = 0; nb < 4; ++nb) {
    int fb = wn + 4 * nb;
    valid[nb] = (nb < nfrag) && (fb * 16 + col < II);
  }

  float mx[4][4];
#pragma unroll
  for (int ma = 0; ma < 4; ++ma)
#pragma unroll
    for (int reg = 0; reg < 4; ++reg) {
      float m = -FLT_MAX;
#pragma unroll
      for (int nb = 0; nb < 4; ++nb)
        if (valid[nb]) m = fmaxf(m, acc[ma][nb][reg]);
      mx[ma][reg] = m;
    }
#pragma unroll
  for (int st = 1; st <= 8; st <<= 1)
#pragma unroll
    for (int ma = 0; ma < 4; ++ma)
#pragma unroll
      for (int reg = 0; reg < 4; ++reg)
        mx[ma][reg] = fmaxf(mx[ma][reg], __shfl_xor(mx[ma][reg], st));

  if (col == 0) {
#pragma unroll
    for (int ma = 0; ma < 4; ++ma)
#pragma unroll
      for (int reg = 0; reg < 4; ++reg)
        smax[wn * 128 + wm * 64 + ma * 16 + gq * 4 + reg] = mx[ma][reg];
  }
  __syncthreads();

  if (tid < 128) {
    int r = tid;                       // row = x_local*32 + t (x_local 0..3)
    float m = fmaxf(fmaxf(smax[r], smax[128 + r]),
                    fmaxf(smax[256 + r], smax[384 + r]));
    int x = xcb * 4 + (r >> 5), tt = r & 31;
    int mk = mask[x * T1 + 1 + tt];
    float num = mk ? m * TEMP : 0.f;
    float cnt = mk ? 1.f : 0.f;
#pragma unroll
    for (int st = 1; st < 32; st <<= 1) {
      num += __shfl_xor(num, st);
      cnt += __shfl_xor(cnt, st);
    }
    if (tt == 0) tti[x * 64 + y] = num / fmaxf(cnt, 1e-6f);
  }
}

// 1 block x 1024 threads: 16 threads per row x, each sums 4 y's.
__global__ void loss_kernel(const float* __restrict__ tti, float* __restrict__ out) {
  __shared__ float lxs[64];
  int tid = threadIdx.x;
  int x = tid >> 4, q = tid & 15;
  float4 v = *(const float4*)&tti[x * 64 + q * 4];
  float den = expf(v.x) + expf(v.y) + expf(v.z) + expf(v.w);
#pragma unroll
  for (int st = 1; st < 16; st <<= 1) den += __shfl_xor(den, st);
  if (q == 0) {
    float pos = expf(tti[x * 64 + x]);
    lxs[x] = -logf(pos / den + 1e-20f);
  }
  __syncthreads();
  if (tid < 64) {
    float lx = lxs[tid];
#pragma unroll
    for (int s = 1; s < 64; s <<= 1) lx += __shfl_xor(lx, s);
    if (tid == 0) out[0] = lx * (1.0f / 64.0f);
  }
}

extern "C" void kernel_launch(void* const* d_in, const int* in_sizes, int n_in,
                              void* d_out, int out_size, void* d_ws, size_t ws_size,
                              hipStream_t stream) {
  const float* text = (const float*)d_in[0];   // [64][33][512] f32
  const float* video = (const float*)d_in[1];  // [64][197][512] f32
  const int* mask = (const int*)d_in[2];       // [64][33] i32
  float* out = (float*)d_out;

  char* ws = (char*)d_ws;
  unsigned char* tl8 = (unsigned char*)(ws + TL_OFF);
  unsigned char* ve8 = (unsigned char*)(ws + VE_OFF);
  float* tti = (float*)(ws + TTI_OFF);

  hipLaunchKernelGGL(norm_all_kernel, dim3(BB, 8), dim3(512), 0, stream, text, video, tl8, ve8);
  hipLaunchKernelGGL(sim_kernel, dim3(1024), dim3(512), 0, stream, tl8, ve8, mask, tti);
  hipLaunchKernelGGL(loss_kernel, dim3(1), dim3(1024), 0, stream, tti, out);
}

// Round 15
// 41.891 us; speedup vs baseline: 1.0625x; 1.0173x over previous
//
#include <hip/hip_runtime.h>
#include <hip/hip_bf16.h>
#include <float.h>
#include <math.h>

#define BB 64
#define T1 33
#define TT 32
#define II 197
#define CC 512
#define TEMP 0.07f

typedef float f32x4 __attribute__((ext_vector_type(4)));
typedef int i32x4 __attribute__((ext_vector_type(4)));
typedef int i32x8 __attribute__((ext_vector_type(8)));

// ---- workspace layout (bytes) ----
// Frag records for mfma_scale_f32_16x16x128_f8f6f4 (fp8): per frag per kstep,
// 2048 B = [half h 0..1][lane 0..63][16 B]; element (row/col = lane&15,
// k = ks*128 + (lane>>4)*32 + h*16 + j).
// tl8: [xc8 8][ks 4][fa 16] records  (1 MB)   A: text rows r=fa*16+(lane&15)
// ve8: [y 64][ks 4][fb 16] records  (8 MB)   B: cols  i=fb*16+(lane&15); fb<=12 written
// tti: [64 x][64 y] f32
#define TL_OFF  0
#define VE_OFF  (1 << 20)                  // 1 MB
#define TTI_OFF ((1 << 20) + (8 << 20))    // 9 MB
#define KS_STRIDE   32768                  // 16 frags * 2048
#define GRP_STRIDE  131072                 // 4 ks * KS_STRIDE

// grid (64, 8): hz 0..3 = video c-chunks (= ksteps), hz 4..7 = text c-chunks.
// 512 threads. Pass 1 caches the block's 100 KB row-chunk in LDS; pass 2
// builds fp8 records from LDS (inputs read from HBM exactly once, coalesced).
__global__ __launch_bounds__(512) void norm_all_kernel(const float* __restrict__ text,
                                                       const float* __restrict__ video,
                                                       unsigned char* __restrict__ tl8,
                                                       unsigned char* __restrict__ ve8) {
  int b = blockIdx.x, hz = blockIdx.y, tid = threadIdx.x;
  bool isV = hz < 4;
  int h2 = isV ? hz : hz - 4;                  // kstep
  const float* src = isV ? (video + (size_t)b * II * CC) : (text + (size_t)b * T1 * CC);
  int n = isV ? II : T1;

  __shared__ float cache[II][132];   // 104 KB: rows x 128-float chunk (pad 4)
  __shared__ float red[16][128];     // 8 KB
  __shared__ float rn[128];

  // pass 1: coalesced chunk read -> LDS cache + sum of squares over rows
  {
    int c4 = tid & 31, rg = tid >> 5;          // rg 0..15
    const float* p = src + h2 * 128 + c4 * 4;
    float4 s = {0.f, 0.f, 0.f, 0.f};
    for (int i = rg; i < n; i += 16) {
      float4 v = *(const float4*)(p + (size_t)i * CC);
      *(float4*)&cache[i][c4 * 4] = v;
      s.x += v.x * v.x; s.y += v.y * v.y; s.z += v.z * v.z; s.w += v.w * v.w;
    }
    *(float4*)&red[rg][c4 * 4] = s;
  }
  __syncthreads();
  if (tid < 128) {
    float s = 0.f;
#pragma unroll
    for (int g = 0; g < 16; ++g) s += red[g][tid];
    rn[tid] = 1.0f / sqrtf(s);
  }
  __syncthreads();

  // pass 2: build 16-B record slices from the LDS cache, fp8 e4m3.
  // slice (frag f, half h, lane l): row/col = f*16+(l&15),
  // chunk-local channels = (l>>4)*32 + h*16 + {0..15}
  if (isV) {
    for (int S = tid; S < 13 * 128; S += 512) {
      int fb = S >> 7, h = (S >> 6) & 1, lane = S & 63;
      int i = fb * 16 + (lane & 15);
      int kloc = ((lane >> 4) & 3) * 32 + h * 16;
      unsigned int wd[4];
#pragma unroll
      for (int q = 0; q < 4; ++q) {
        f32x4 u = {0.f, 0.f, 0.f, 0.f};
        if (i < II) u = *(const f32x4*)&cache[i][kloc + q * 4];
        f32x4 r = *(const f32x4*)&rn[kloc + q * 4];
        int wv = __builtin_amdgcn_cvt_pk_fp8_f32(u[0] * r[0], u[1] * r[1], 0, 0);
        wv = __builtin_amdgcn_cvt_pk_fp8_f32(u[2] * r[2], u[3] * r[3], wv, 1);
        wd[q] = (unsigned int)wv;
      }
      unsigned char* dst = ve8 + (size_t)b * GRP_STRIDE + h2 * KS_STRIDE +
                           fb * 2048 + h * 1024 + lane * 16;
      *(uint4*)dst = make_uint4(wd[0], wd[1], wd[2], wd[3]);
    }
  } else if (tid < 256) {
    // 2 fa_local x 2 h x 64 lane = 256 slices
    int fa_local = tid >> 7, h = (tid >> 6) & 1, lane = tid & 63;
    int t = fa_local * 16 + (lane & 15);          // 0..31
    int kloc = ((lane >> 4) & 3) * 32 + h * 16;
    unsigned int wd[4];
#pragma unroll
    for (int q = 0; q < 4; ++q) {
      f32x4 u = *(const f32x4*)&cache[1 + t][kloc + q * 4];
      f32x4 r = *(const f32x4*)&rn[kloc + q * 4];
      int wv = __builtin_amdgcn_cvt_pk_fp8_f32(u[0] * r[0], u[1] * r[1], 0, 0);
      wv = __builtin_amdgcn_cvt_pk_fp8_f32(u[2] * r[2], u[3] * r[3], wv, 1);
      wd[q] = (unsigned int)wv;
    }
    int fa = (b & 7) * 2 + fa_local;
    unsigned char* dst = tl8 + (size_t)(b >> 3) * GRP_STRIDE + h2 * KS_STRIDE +
                         fa * 2048 + h * 1024 + lane * 16;
    *(uint4*)dst = make_uint4(wd[0], wd[1], wd[2], wd[3]);
  }
}

// ROUND-15 = ROUND-9 sim, verbatim (best measured config: 41.87 us total,
// sim ~= 22 us by the round-11 double-launch diagnostic). Zero-LDS
// direct-to-register: 2048 blocks x 512 threads, 64 rows (2 batch-x) x
// 208 cols, K=512 as 4 ksteps of 128 (mfma_scale 16x16x128 fp8, scales=1).
// No K-loop barriers, no staging; #pragma unroll 1 bounds the live set
// (~80 regs < the (512,4) 128-reg cap -- full unroll hoists 4 ksteps of
// loads and spills, rounds 5/7). Wave map wm=w&1, wn=w>>1 balances the
// frag-12 (wn==0) waves across SIMDs.
// Plateau evidence (rounds 10-14): sim invariant at ~22 us under L2-byte
// reduction (r13 B-in-LDS), delivery-byte reduction (r14 2x tile),
// latency prefetch (r10), and LDS sourcing (r8/r12) -- all models that
// predict a win from those changes are falsified; residual is structural
// MFMA/VMEM/VALU interleave stall at HIP-source scheduling (cf. the
// documented 2-phase-structure ceiling), with no 8-phase room in a
// 4-kstep loop. fp4 fails numerically (e2m1 noise ~35% of dot magnitude).
__global__ __launch_bounds__(512, 4) void sim_kernel(const unsigned char* __restrict__ tl8,
                                                     const unsigned char* __restrict__ ve8,
                                                     const int* __restrict__ mask,
                                                     float* __restrict__ tti) {
  int L = blockIdx.x;
  int xcd = L & 7;
  int idx = L >> 3;              // 0..255
  int y = xcd * 8 + (idx & 7);   // each XCD owns 8 consecutive y's
  int xcb = idx >> 3;            // 0..31 : 2 batch-x per block (64 rows)

  int tid = threadIdx.x;
  int w = tid >> 6, lane = tid & 63;
  int wm = w & 1;                // rows wm*32..+32 (2 frags)
  int wn = w >> 1;               // col frags wn, wn+4, wn+8 (+12 if wn==0)

  __shared__ float smax[4 * 64]; // [wn][row] 1 KB

  const unsigned char* Abase =
      tl8 + (size_t)(xcb >> 2) * GRP_STRIDE + (size_t)(xcb & 3) * 4 * 2048;
  const unsigned char* Bbase = ve8 + (size_t)y * GRP_STRIDE;

  f32x4 acc[2][4] = {};

#pragma unroll 1
  for (int s = 0; s < 4; ++s) {
    const unsigned char* ab = Abase + (size_t)s * KS_STRIDE + lane * 16;
    const unsigned char* bb = Bbase + (size_t)s * KS_STRIDE + lane * 16;

    i32x8 aop[2];
#pragma unroll
    for (int ma = 0; ma < 2; ++ma) {
      const unsigned char* p = ab + (wm * 2 + ma) * 2048;
      i32x4 h0 = *(const i32x4*)p;
      i32x4 h1 = *(const i32x4*)(p + 1024);
      aop[ma] = __builtin_shufflevector(h0, h1, 0, 1, 2, 3, 4, 5, 6, 7);
    }

#pragma unroll
    for (int nb = 0; nb < 3; ++nb) {
      int fb = wn + 4 * nb;
      const unsigned char* p = bb + fb * 2048;
      i32x4 h0 = *(const i32x4*)p;
      i32x4 h1 = *(const i32x4*)(p + 1024);
      i32x8 bop = __builtin_shufflevector(h0, h1, 0, 1, 2, 3, 4, 5, 6, 7);
#pragma unroll
      for (int ma = 0; ma < 2; ++ma)
        acc[ma][nb] = __builtin_amdgcn_mfma_scale_f32_16x16x128_f8f6f4(
            aop[ma], bop, acc[ma][nb], 0, 0,
            0, 0x7F7F7F7F, 0, 0x7F7F7F7F);
    }
    if (wn == 0) {
      const unsigned char* p = bb + 12 * 2048;
      i32x4 h0 = *(const i32x4*)p;
      i32x4 h1 = *(const i32x4*)(p + 1024);
      i32x8 bop = __builtin_shufflevector(h0, h1, 0, 1, 2, 3, 4, 5, 6, 7);
#pragma unroll
      for (int ma = 0; ma < 2; ++ma)
        acc[ma][3] = __builtin_amdgcn_mfma_scale_f32_16x16x128_f8f6f4(
            aop[ma], bop, acc[ma][3], 0, 0,
            0, 0x7F7F7F7F, 0, 0x7F7F7F7F);
    }
  }

  // ---- fused epilogue: max over i (i<197), masked mean over t -> tti ----
  int col = lane & 15, gq = lane >> 4;
  int nfrag = (wn == 0) ? 4 : 3;
  bool valid[4];
#pragma unroll
  for (int nb = 0; nb < 4; ++nb) {
    int fb = wn + 4 * nb;
    valid[nb] = (nb < nfrag) && (fb * 16 + col < II);
  }

  float mx[2][4];
#pragma unroll
  for (int ma = 0; ma < 2; ++ma)
#pragma unroll
    for (int reg = 0; reg < 4; ++reg) {
      float m = -FLT_MAX;
#pragma unroll
      for (int nb = 0; nb < 4; ++nb)
        if (valid[nb]) m = fmaxf(m, acc[ma][nb][reg]);
      mx[ma][reg] = m;
    }
#pragma unroll
  for (int st = 1; st <= 8; st <<= 1)
#pragma unroll
    for (int ma = 0; ma < 2; ++ma)
#pragma unroll
      for (int reg = 0; reg < 4; ++reg)
        mx[ma][reg] = fmaxf(mx[ma][reg], __shfl_xor(mx[ma][reg], st));

  if (col == 0) {
#pragma unroll
    for (int ma = 0; ma < 2; ++ma)
#pragma unroll
      for (int reg = 0; reg < 4; ++reg)
        smax[wn * 64 + wm * 32 + ma * 16 + gq * 4 + reg] = mx[ma][reg];
  }
  __syncthreads();

  if (tid < 64) {
    int r = tid;                       // row = x_local*32 + t (x_local 0..1)
    float m = fmaxf(fmaxf(smax[r], smax[64 + r]),
                    fmaxf(smax[128 + r], smax[192 + r]));
    int x = xcb * 2 + (r >> 5), tt = r & 31;
    int mk = mask[x * T1 + 1 + tt];
    float num = mk ? m * TEMP : 0.f;
    float cnt = mk ? 1.f : 0.f;
#pragma unroll
    for (int st = 1; st < 32; st <<= 1) {
      num += __shfl_xor(num, st);
      cnt += __shfl_xor(cnt, st);
    }
    if (tt == 0) tti[x * 64 + y] = num / fmaxf(cnt, 1e-6f);
  }
}

// 1 block x 1024 threads: 16 threads per row x, each sums 4 y's.
__global__ void loss_kernel(const float* __restrict__ tti, float* __restrict__ out) {
  __shared__ float lxs[64];
  int tid = threadIdx.x;
  int x = tid >> 4, q = tid & 15;
  float4 v = *(const float4*)&tti[x * 64 + q * 4];
  float den = expf(v.x) + expf(v.y) + expf(v.z) + expf(v.w);
#pragma unroll
  for (int st = 1; st < 16; st <<= 1) den += __shfl_xor(den, st);
  if (q == 0) {
    float pos = expf(tti[x * 64 + x]);
    lxs[x] = -logf(pos / den + 1e-20f);
  }
  __syncthreads();
  if (tid < 64) {
    float lx = lxs[tid];
#pragma unroll
    for (int s = 1; s < 64; s <<= 1) lx += __shfl_xor(lx, s);
    if (tid == 0) out[0] = lx * (1.0f / 64.0f);
  }
}

extern "C" void kernel_launch(void* const* d_in, const int* in_sizes, int n_in,
                              void* d_out, int out_size, void* d_ws, size_t ws_size,
                              hipStream_t stream) {
  const float* text = (const float*)d_in[0];   // [64][33][512] f32
  const float* video = (const float*)d_in[1];  // [64][197][512] f32
  const int* mask = (const int*)d_in[2];       // [64][33] i32
  float* out = (float*)d_out;

  char* ws = (char*)d_ws;
  unsigned char* tl8 = (unsigned char*)(ws + TL_OFF);
  unsigned char* ve8 = (unsigned char*)(ws + VE_OFF);
  float* tti = (float*)(ws + TTI_OFF);

  hipLaunchKernelGGL(norm_all_kernel, dim3(BB, 8), dim3(512), 0, stream, text, video, tl8, ve8);
  hipLaunchKernelGGL(sim_kernel, dim3(2048), dim3(512), 0, stream, tl8, ve8, mask, tti);
  hipLaunchKernelGGL(loss_kernel, dim3(1), dim3(1024), 0, stream, tti, out);
}